// Round 1
// baseline (369.567 us; speedup 1.0000x reference)
//
#include <hip/hip_runtime.h>

// Problem constants (from reference): B=128, N=512, PD=512, E=64, gamma=1
#define Bb 128
#define Nn 512
#define Ee 64
#define NC 192   // multi-RHS columns: 128 batch RHS + 64 columns of A0^T

// ---------------------------------------------------------------------------
// k_build: r' = F = [X - P | A0^T]  stored transposed as (192 x 512) row-major.
// Also init d0 = (1/theta)*F, u = d0  (Chebyshev u_1).
// ---------------------------------------------------------------------------
__global__ __launch_bounds__(256) void k_build(
    const float* __restrict__ x, const float* __restrict__ p,
    const float* __restrict__ A0,
    float* __restrict__ r, float* __restrict__ d, float* __restrict__ u,
    float invTheta)
{
    int idx = blockIdx.x * 256 + threadIdx.x;   // 0 .. 192*512-1
    int row = idx >> 9;        // / 512
    int col = idx & 511;
    float v;
    if (row < Bb) v = x[idx] - p[idx];               // x,parms both (128,512) row-major
    else          v = A0[(row - Bb) * Nn + col];     // A0 is (64,512)
    r[idx] = v;
    float dv = invTheta * v;
    d[idx] = dv;
    u[idx] = dv;
}

// ---------------------------------------------------------------------------
// k_cheb: one Chebyshev iteration, fused GEMM + vector update.
//   hd = H * d_in  computed as 0.5*(d_in' @ M) + d_in   (H = M/2 + I, M symmetric)
//   r <- r - hd ; d_out = c1*d_in + c2*r ; u += d_out
// d stored transposed (192 x 512); GEMM is (192x512)@(512x512).
// Tiles: BM=16 rows, BN=32 cols, BK=32. Grid = 12*16 = 192 WGs, 256 thr.
// ---------------------------------------------------------------------------
__global__ __launch_bounds__(256) void k_cheb(
    const float* __restrict__ Mm,
    const float* __restrict__ din, float* __restrict__ dout,
    float* __restrict__ r, float* __restrict__ u,
    float c1, float c2)
{
    __shared__ float Ds[16][33];
    __shared__ float Ms[32][33];
    int t  = threadIdx.x;
    int tx = t & 15, ty = t >> 4;
    int bm0 = (blockIdx.x >> 4) * 16;    // 12 m-blocks
    int bn0 = (blockIdx.x & 15) * 32;    // 16 n-blocks
    float acc0 = 0.f, acc1 = 0.f;

    for (int k0 = 0; k0 < Nn; k0 += 32) {
        // load d tile: 16x32 = 512 elems, 2 per thread (coalesced 128B rows)
        #pragma unroll
        for (int i = 0; i < 2; ++i) {
            int ii = t + i * 256;
            Ds[ii >> 5][ii & 31] = din[(bm0 + (ii >> 5)) * Nn + k0 + (ii & 31)];
        }
        // load M tile: 32x32 = 1024 elems, 4 per thread
        #pragma unroll
        for (int i = 0; i < 4; ++i) {
            int ii = t + i * 256;
            Ms[ii >> 5][ii & 31] = Mm[(k0 + (ii >> 5)) * Nn + bn0 + (ii & 31)];
        }
        __syncthreads();
        #pragma unroll
        for (int kk = 0; kk < 32; ++kk) {
            float a = Ds[ty][kk];
            acc0 += a * Ms[kk][tx];
            acc1 += a * Ms[kk][tx + 16];
        }
        __syncthreads();
    }

    int m = bm0 + ty;
    int idx0 = m * Nn + bn0 + tx;
    int idx1 = idx0 + 16;
    float di0 = din[idx0], di1 = din[idx1];
    float hd0 = 0.5f * acc0 + di0;       // H*d = 0.5*(d@M) + d
    float hd1 = 0.5f * acc1 + di1;
    float r0 = r[idx0] - hd0; r[idx0] = r0;
    float r1 = r[idx1] - hd1; r[idx1] = r1;
    float dn0 = c1 * di0 + c2 * r0; dout[idx0] = dn0;
    float dn1 = c1 * di1 + c2 * r1; dout[idx1] = dn1;
    u[idx0] += dn0;
    u[idx1] += dn1;
}

// ---------------------------------------------------------------------------
// k_small: su[e][j] (64 x 192): j<64 -> S[e][j] = A0[e,:]·u'[128+j,:]  (S = A0 H^-1 A0^T)
//                               j>=64 -> rhs[e][j-64] = A0[e,:]·u'[j-64,:] + c[e]
// Grid 4*12=48 WGs, 256 thr (16x16), 1 output each, K=512.
// ---------------------------------------------------------------------------
__global__ __launch_bounds__(256) void k_small(
    const float* __restrict__ A0, const float* __restrict__ u,
    const float* __restrict__ c, float* __restrict__ su)
{
    __shared__ float As[16][33];
    __shared__ float Us[16][33];
    int t  = threadIdx.x;
    int tx = t & 15, ty = t >> 4;
    int e0 = (blockIdx.x / 12) * 16;   // 4 e-blocks
    int j0 = (blockIdx.x % 12) * 16;   // 12 j-blocks
    float acc = 0.f;

    for (int k0 = 0; k0 < Nn; k0 += 32) {
        #pragma unroll
        for (int i = 0; i < 2; ++i) {
            int ii = t + i * 256;
            int rr = ii >> 5, cc = ii & 31;
            As[rr][cc] = A0[(e0 + rr) * Nn + k0 + cc];
            int j_ = j0 + rr;
            int urow = (j_ < 64) ? (128 + j_) : (j_ - 64);
            Us[rr][cc] = u[urow * Nn + k0 + cc];
        }
        __syncthreads();
        #pragma unroll
        for (int kk = 0; kk < 32; ++kk)
            acc += As[ty][kk] * Us[tx][kk];
        __syncthreads();
    }
    int e = e0 + ty, j = j0 + tx;
    su[e * 192 + j] = acc + ((j >= 64) ? c[e] : 0.f);
}

// ---------------------------------------------------------------------------
// k_gj: in-LDS Gauss-Jordan on [S | RHS] (64 x 192), no pivoting (S SPD).
// Writes back Lambda = S^-1 RHS into su[:, 64:192]. One WG, 1024 threads.
// ---------------------------------------------------------------------------
__global__ __launch_bounds__(1024) void k_gj(float* __restrict__ su_g)
{
    __shared__ float S[64][192];
    __shared__ float rowp[192];
    __shared__ float colp[64];
    int t = threadIdx.x;
    for (int i = t; i < 64 * 192; i += 1024) S[i / 192][i % 192] = su_g[i];
    __syncthreads();
    for (int p = 0; p < 64; ++p) {
        if (t < 192) {
            float piv = S[p][p];
            rowp[t] = S[p][t] / piv;
        } else if (t < 256) {
            colp[t - 192] = S[t - 192][p];
        }
        __syncthreads();
        for (int i = t; i < 64 * 192; i += 1024) {
            int e = i / 192, j = i % 192;
            if (e == p) S[e][j] = rowp[j];
            else        S[e][j] -= colp[e] * rowp[j];
        }
        __syncthreads();
    }
    for (int i = t; i < 64 * 128; i += 1024) {
        int e = i >> 7, b = i & 127;
        su_g[e * 192 + 64 + b] = S[e][64 + b];
    }
}

// ---------------------------------------------------------------------------
// k_final: out[b][n] = u'[b][n] - sum_e Lambda[e][b] * u'[128+e][n]
// One WG per batch b (128 WGs, 256 thr, 2 outputs/thread).
// ---------------------------------------------------------------------------
__global__ __launch_bounds__(256) void k_final(
    const float* __restrict__ u, const float* __restrict__ su_g,
    float* __restrict__ out)
{
    __shared__ float lam[64];
    int b = blockIdx.x;
    int t = threadIdx.x;
    if (t < 64) lam[t] = su_g[t * 192 + 64 + b];
    __syncthreads();
    #pragma unroll
    for (int i = 0; i < 2; ++i) {
        int n = t + i * 256;
        float acc = u[b * Nn + n];
        #pragma unroll 8
        for (int e = 0; e < Ee; ++e)
            acc -= lam[e] * u[(128 + e) * Nn + n];
        out[b * Nn + n] = acc;
    }
}

// ---------------------------------------------------------------------------
extern "C" void kernel_launch(void* const* d_in, const int* in_sizes, int n_in,
                              void* d_out, int out_size, void* d_ws, size_t ws_size,
                              hipStream_t stream)
{
    const float* x     = (const float*)d_in[0];  // (128,512)
    const float* parms = (const float*)d_in[1];  // (128,512)
    const float* Mm    = (const float*)d_in[2];  // (512,512) SPD
    const float* A0    = (const float*)d_in[3];  // (64,512)
    // d_in[4] = B0 unused (F0 evaluated at zeros -> only c survives)
    const float* c     = (const float*)d_in[5];  // (64,)
    float* out = (float*)d_out;

    float* ws = (float*)d_ws;
    const int MAT = NC * Nn;            // 98304 floats per (192x512) matrix
    float* r  = ws;
    float* d0 = ws + MAT;
    float* d1 = ws + 2 * MAT;
    float* u  = ws + 3 * MAT;
    float* su = ws + 4 * MAT;           // 64*192

    // Chebyshev setup: H = M/2 + I, spectrum in [1, ~3.05]; bounds [1.0, 3.6].
    const double aa = 1.0, bb = 3.6;
    const double theta = 0.5 * (bb + aa);
    const double delta = 0.5 * (bb - aa);
    const double sigma = theta / delta;

    k_build<<<(NC * Nn) / 256, 256, 0, stream>>>(x, parms, A0, r, d0, u,
                                                 (float)(1.0 / theta));

    double rho_prev = 1.0 / sigma;
    float* din  = d0;
    float* dnew = d1;
    for (int k = 1; k <= 13; ++k) {      // total polynomial degree 14
        double rho = 1.0 / (2.0 * sigma - rho_prev);
        float c1 = (float)(rho * rho_prev);
        float c2 = (float)(2.0 * rho / delta);
        k_cheb<<<192, 256, 0, stream>>>(Mm, din, dnew, r, u, c1, c2);
        rho_prev = rho;
        float* tmp = din; din = dnew; dnew = tmp;
    }

    k_small<<<48, 256, 0, stream>>>(A0, u, c, su);
    k_gj<<<1, 1024, 0, stream>>>(su);
    k_final<<<128, 256, 0, stream>>>(u, su, out);
}

// Round 2
// 232.318 us; speedup vs baseline: 1.5908x; 1.5908x over previous
//
#include <hip/hip_runtime.h>

// Problem constants (from reference): B=128, N=512, PD=512, E=64, gamma=1
#define Bb 128
#define Nn 512
#define Ee 64
#define NC 192   // multi-RHS columns: 128 batch RHS + 64 columns of A0^T

// ---------------------------------------------------------------------------
// k_build: r' = F = [X - P | A0^T]  stored transposed as (192 x 512) row-major.
// Also init d0 = (1/theta)*F, u = d0  (Chebyshev u_1).
// ---------------------------------------------------------------------------
__global__ __launch_bounds__(256) void k_build(
    const float* __restrict__ x, const float* __restrict__ p,
    const float* __restrict__ A0,
    float* __restrict__ r, float* __restrict__ d, float* __restrict__ u,
    float invTheta)
{
    int idx = blockIdx.x * 256 + threadIdx.x;   // 0 .. 192*512-1
    int row = idx >> 9;        // / 512
    int col = idx & 511;
    float v;
    if (row < Bb) v = x[idx] - p[idx];               // x,parms both (128,512) row-major
    else          v = A0[(row - Bb) * Nn + col];     // A0 is (64,512)
    r[idx] = v;
    float dv = invTheta * v;
    d[idx] = dv;
    u[idx] = dv;
}

// ---------------------------------------------------------------------------
// k_cheb2: one Chebyshev iteration, fused GEMM + vector update, split-K in WG.
//   hd = H*d_in = 0.5*(d_in' @ M) + d_in    (H = M/2 + I, M symmetric)
//   r <- r - hd ; d_out = c1*d_in + c2*r ; u += d_out
// Output tile 8x16 per WG; 4 waves each own K-quarter (128) with PRIVATE LDS
// tiles -> no barriers in the K loop (per-wave DS ops are in-order).
// Grid = 24 m-blocks * 32 n-blocks = 768 WGs (3 WG/CU, 3 waves/SIMD).
// ---------------------------------------------------------------------------
__global__ __launch_bounds__(256) void k_cheb2(
    const float* __restrict__ Mm,
    const float* __restrict__ din, float* __restrict__ dout,
    float* __restrict__ r, float* __restrict__ u,
    float c1, float c2)
{
    __shared__ float As[4][8][33];    // per-wave: 8 rows x 32 k
    __shared__ float Bs[4][32][17];   // per-wave: 32 k x 16 cols
    __shared__ float Pp[4][128];      // per-wave partial outputs

    int t    = threadIdx.x;
    int w    = t >> 6;
    int lane = t & 63;
    int bm0  = (int)(blockIdx.x >> 5) * 8;     // 24 m-blocks
    int bn0  = (int)(blockIdx.x & 31) * 16;    // 32 n-blocks
    int kbase = w * 128;

    int r0  = lane >> 4;      // 0..3  (second output row = r0+4)
    int col = lane & 15;

    float acc0 = 0.f, acc1 = 0.f;

    for (int kt = 0; kt < 4; ++kt) {
        int k0 = kbase + kt * 32;
        // stage A tile: 8x32 = 256 elems, 4 per lane (rows of 32 floats, coalesced)
        #pragma unroll
        for (int i = 0; i < 4; ++i) {
            int ii = lane + i * 64;
            As[w][ii >> 5][ii & 31] = din[(bm0 + (ii >> 5)) * Nn + k0 + (ii & 31)];
        }
        // stage B tile: 32x16 = 512 elems, 8 per lane
        #pragma unroll
        for (int i = 0; i < 8; ++i) {
            int ii = lane + i * 64;
            Bs[w][ii >> 4][ii & 15] = Mm[(k0 + (ii >> 4)) * Nn + bn0 + (ii & 15)];
        }
        // no __syncthreads: tiles are wave-private, DS ops in-order per wave
        #pragma unroll
        for (int kk = 0; kk < 32; ++kk) {
            float b = Bs[w][kk][col];
            acc0 += As[w][r0][kk] * b;
            acc1 += As[w][r0 + 4][kk] * b;
        }
    }
    Pp[w][r0 * 16 + col]       = acc0;
    Pp[w][(r0 + 4) * 16 + col] = acc1;
    __syncthreads();

    if (t < 128) {
        int row = t >> 4, cc = t & 15;
        float s = Pp[0][t] + Pp[1][t] + Pp[2][t] + Pp[3][t];
        int idx = (bm0 + row) * Nn + bn0 + cc;
        float di = din[idx];
        float hd = 0.5f * s + di;                 // H*d = 0.5*(d@M) + d
        float rv = r[idx] - hd; r[idx] = rv;
        float dn = c1 * di + c2 * rv; dout[idx] = dn;
        u[idx] += dn;
    }
}

// ---------------------------------------------------------------------------
// k_small: su[e][j] (64 x 192): j<64 -> S[e][j] = A0[e,:]·u'[128+j,:]
//                               j>=64 -> rhs[e][j-64] = A0[e,:]·u'[j-64,:] + c[e]
// ---------------------------------------------------------------------------
__global__ __launch_bounds__(256) void k_small(
    const float* __restrict__ A0, const float* __restrict__ u,
    const float* __restrict__ c, float* __restrict__ su)
{
    __shared__ float As[16][33];
    __shared__ float Us[16][33];
    int t  = threadIdx.x;
    int tx = t & 15, ty = t >> 4;
    int e0 = (blockIdx.x / 12) * 16;   // 4 e-blocks
    int j0 = (blockIdx.x % 12) * 16;   // 12 j-blocks
    float acc = 0.f;

    for (int k0 = 0; k0 < Nn; k0 += 32) {
        #pragma unroll
        for (int i = 0; i < 2; ++i) {
            int ii = t + i * 256;
            int rr = ii >> 5, cc = ii & 31;
            As[rr][cc] = A0[(e0 + rr) * Nn + k0 + cc];
            int j_ = j0 + rr;
            int urow = (j_ < 64) ? (128 + j_) : (j_ - 64);
            Us[rr][cc] = u[urow * Nn + k0 + cc];
        }
        __syncthreads();
        #pragma unroll
        for (int kk = 0; kk < 32; ++kk)
            acc += As[ty][kk] * Us[tx][kk];
        __syncthreads();
    }
    int e = e0 + ty, j = j0 + tx;
    su[e * 192 + j] = acc + ((j >= 64) ? c[e] : 0.f);
}

// ---------------------------------------------------------------------------
// wave-wide (64 lane) sum reduction
// ---------------------------------------------------------------------------
__device__ inline float wred(float v)
{
    #pragma unroll
    for (int s = 32; s > 0; s >>= 1) v += __shfl_xor(v, s, 64);
    return v;
}

// ---------------------------------------------------------------------------
// k_lam: solve S * Lambda = RHS for 128 independent columns via CG.
// One wave per column; S row held in REGISTERS (fully unrolled); p broadcast
// via wave-private LDS; dots via shfl. No __syncthreads in the loop.
// Grid = 32 WGs x 256 thr. Writes Lambda back into su[:, 64:192].
// ---------------------------------------------------------------------------
__global__ __launch_bounds__(256) void k_lam(float* __restrict__ su_g)
{
    __shared__ float Sm[64][65];
    __shared__ float pb[4][64];
    int t = threadIdx.x;
    for (int i = t; i < 64 * 64; i += 256)
        Sm[i >> 6][i & 63] = su_g[(i >> 6) * 192 + (i & 63)];
    __syncthreads();

    int w = t >> 6, lane = t & 63;
    int b = blockIdx.x * 4 + w;            // column 0..127

    float srow[64];
    #pragma unroll
    for (int k = 0; k < 64; ++k) srow[k] = Sm[lane][k];

    float rhs = su_g[lane * 192 + 64 + b];
    float xv = 0.f, rv = rhs, p = rv;
    float rr = wred(rv * rv);

    for (int it = 0; it < 40; ++it) {
        pb[w][lane] = p;                   // wave-private, DS in-order
        float q = 0.f;
        #pragma unroll
        for (int k = 0; k < 64; ++k) q += srow[k] * pb[w][k];
        float pq = wred(p * q);
        float alpha = rr / fmaxf(pq, 1e-30f);
        xv += alpha * p;
        rv -= alpha * q;
        float rr2 = wred(rv * rv);
        float beta = rr2 / fmaxf(rr, 1e-30f);
        rr = rr2;
        p = rv + beta * p;
    }
    su_g[lane * 192 + 64 + b] = xv;
}

// ---------------------------------------------------------------------------
// k_final: out[b][n] = u'[b][n] - sum_e Lambda[e][b] * u'[128+e][n]
// ---------------------------------------------------------------------------
__global__ __launch_bounds__(256) void k_final(
    const float* __restrict__ u, const float* __restrict__ su_g,
    float* __restrict__ out)
{
    __shared__ float lam[64];
    int b = blockIdx.x;
    int t = threadIdx.x;
    if (t < 64) lam[t] = su_g[t * 192 + 64 + b];
    __syncthreads();
    #pragma unroll
    for (int i = 0; i < 2; ++i) {
        int n = t + i * 256;
        float acc = u[b * Nn + n];
        #pragma unroll 8
        for (int e = 0; e < Ee; ++e)
            acc -= lam[e] * u[(128 + e) * Nn + n];
        out[b * Nn + n] = acc;
    }
}

// ---------------------------------------------------------------------------
extern "C" void kernel_launch(void* const* d_in, const int* in_sizes, int n_in,
                              void* d_out, int out_size, void* d_ws, size_t ws_size,
                              hipStream_t stream)
{
    const float* x     = (const float*)d_in[0];  // (128,512)
    const float* parms = (const float*)d_in[1];  // (128,512)
    const float* Mm    = (const float*)d_in[2];  // (512,512) SPD
    const float* A0    = (const float*)d_in[3];  // (64,512)
    // d_in[4] = B0 unused (F0 evaluated at zeros -> only c survives)
    const float* c     = (const float*)d_in[5];  // (64,)
    float* out = (float*)d_out;

    float* ws = (float*)d_ws;
    const int MAT = NC * Nn;            // 98304 floats per (192x512) matrix
    float* r  = ws;
    float* d0 = ws + MAT;
    float* d1 = ws + 2 * MAT;
    float* u  = ws + 3 * MAT;
    float* su = ws + 4 * MAT;           // 64*192

    // Chebyshev setup: H = M/2 + I, spectrum in [1, ~3.05]; bounds [1.0, 3.6].
    const double aa = 1.0, bb = 3.6;
    const double theta = 0.5 * (bb + aa);
    const double delta = 0.5 * (bb - aa);
    const double sigma = theta / delta;

    k_build<<<(NC * Nn) / 256, 256, 0, stream>>>(x, parms, A0, r, d0, u,
                                                 (float)(1.0 / theta));

    double rho_prev = 1.0 / sigma;
    float* din  = d0;
    float* dnew = d1;
    for (int k = 1; k <= 13; ++k) {      // total polynomial degree 14
        double rho = 1.0 / (2.0 * sigma - rho_prev);
        float c1 = (float)(rho * rho_prev);
        float c2 = (float)(2.0 * rho / delta);
        k_cheb2<<<768, 256, 0, stream>>>(Mm, din, dnew, r, u, c1, c2);
        rho_prev = rho;
        float* tmp = din; din = dnew; dnew = tmp;
    }

    k_small<<<48, 256, 0, stream>>>(A0, u, c, su);
    k_lam<<<32, 256, 0, stream>>>(su);
    k_final<<<128, 256, 0, stream>>>(u, su, out);
}